// Round 1
// baseline (38657.236 us; speedup 1.0000x reference)
//
#include <hip/hip_runtime.h>

#define TT    512
#define BB    512
#define HH    200
#define G4    800   // 4*H
#define K1    248   // x(48) + h1(200)
#define K2    448   // h1(200) + out0(48) + h2(200)
#define NSTEP 511

// d_ws layout in 32-bit words:
#define OFF_WP1 0                       // [124][800] u32 (bf16 pairs of [W1ih|W1hh]^T)
#define OFF_WP2 (OFF_WP1 + 124*800)     // [224][800] u32 ([W2ih|W2hh]^T)
#define OFF_WF1 (OFF_WP2 + 224*800)     // [124][200] u32 (fc1^T)
#define OFF_WF2 (OFF_WF1 + 124*200)     // [100][48]  u32 (fc2^T)
#define OFF_FC0 (OFF_WF2 + 100*48)      // [24][48]   f32 (fc0^T)
#define OFF_B1  (OFF_FC0 + 24*48)       // [800] f32 (b1ih+b1hh)
#define OFF_B2  (OFF_B1 + 800)          // [800] f32
#define WS_TOTAL (OFF_B2 + 800)         // 310752 words = 1.24 MB

__device__ __forceinline__ unsigned short f2bf(float f) {
    unsigned u = __float_as_uint(f);
    unsigned r = (u + 0x7fffu + ((u >> 16) & 1u)) >> 16;   // round-to-nearest-even
    return (unsigned short)r;
}
__device__ __forceinline__ float unlo(unsigned u) { return __uint_as_float(u << 16); }
__device__ __forceinline__ float unhi(unsigned u) { return __uint_as_float(u & 0xffff0000u); }
__device__ __forceinline__ float sigm(float x) { return 1.0f / (1.0f + __expf(-x)); }

__global__ void prep_kernel(const float* __restrict__ l1_wih, const float* __restrict__ l1_whh,
                            const float* __restrict__ l1_bih, const float* __restrict__ l1_bhh,
                            const float* __restrict__ l2_wih, const float* __restrict__ l2_whh,
                            const float* __restrict__ l2_bih, const float* __restrict__ l2_bhh,
                            const float* __restrict__ fc1_w, const float* __restrict__ fc2_w,
                            const float* __restrict__ fc0_w, unsigned* __restrict__ ws)
{
    int idx = blockIdx.x * blockDim.x + threadIdx.x;
    int stride = gridDim.x * blockDim.x;
    for (int i = idx; i < WS_TOTAL; i += stride) {
        if (i < OFF_WP2) {                       // W1cat = [l1_wih | l1_whh], K=248
            int r = i - OFF_WP1, k2 = r / G4, j = r % G4;
            int ka = 2 * k2, kb = ka + 1;
            float a = (ka < 48) ? l1_wih[j * 48 + ka] : l1_whh[j * HH + (ka - 48)];
            float b = (kb < 48) ? l1_wih[j * 48 + kb] : l1_whh[j * HH + (kb - 48)];
            ws[i] = (unsigned)f2bf(a) | ((unsigned)f2bf(b) << 16);
        } else if (i < OFF_WF1) {                // W2cat = [l2_wih | l2_whh], K=448
            int r = i - OFF_WP2, k2 = r / G4, j = r % G4;
            int ka = 2 * k2, kb = ka + 1;
            float a = (ka < 248) ? l2_wih[j * 248 + ka] : l2_whh[j * HH + (ka - 248)];
            float b = (kb < 248) ? l2_wih[j * 248 + kb] : l2_whh[j * HH + (kb - 248)];
            ws[i] = (unsigned)f2bf(a) | ((unsigned)f2bf(b) << 16);
        } else if (i < OFF_WF2) {                // fc1_w (200,248) -> [124][200]
            int r = i - OFF_WF1, k2 = r / HH, j = r % HH;
            float a = fc1_w[j * 248 + 2 * k2];
            float b = fc1_w[j * 248 + 2 * k2 + 1];
            ws[i] = (unsigned)f2bf(a) | ((unsigned)f2bf(b) << 16);
        } else if (i < OFF_FC0) {                // fc2_w (48,200) -> [100][48]
            int r = i - OFF_WF2, k2 = r / 48, j = r % 48;
            float a = fc2_w[j * HH + 2 * k2];
            float b = fc2_w[j * HH + 2 * k2 + 1];
            ws[i] = (unsigned)f2bf(a) | ((unsigned)f2bf(b) << 16);
        } else if (i < OFF_B1) {                 // fc0_w (48,24) -> f32 [24][48]
            int r = i - OFF_FC0, k = r / 48, j = r % 48;
            ws[i] = __float_as_uint(fc0_w[j * 24 + k]);
        } else if (i < OFF_B2) {
            int j = i - OFF_B1;
            ws[i] = __float_as_uint(l1_bih[j] + l1_bhh[j]);
        } else {
            int j = i - OFF_B2;
            ws[i] = __float_as_uint(l2_bih[j] + l2_bhh[j]);
        }
    }
}

// One workgroup (512 threads) owns 2 batch rows for the full 511-step recurrence.
// All state lives in LDS; weights stream from L2 each step (bf16 pairs).
__global__ __launch_bounds__(512, 1)
void lstm_kernel(const float* __restrict__ tactiles, const float* __restrict__ actions,
                 const float* __restrict__ fc0_b, const float* __restrict__ fc1_b,
                 const float* __restrict__ fc2_b, const int* __restrict__ ctxp,
                 const unsigned* __restrict__ ws, float* __restrict__ out)
{
    const int tid = threadIdx.x;
    const int r0 = blockIdx.x * 2;

    __shared__ float buf1[2][K1];     // [x | h1]           (gates1 input)
    __shared__ float buf2[2][K2];     // [h1 | out0 | h2]   (gates2 input)
    __shared__ float buf3[2][K1];     // [h2 | x]           (fc1 input)
    __shared__ float gbuf[2][G4];
    __shared__ float o3[2][HH];
    __shared__ float c1s[2][HH];
    __shared__ float c2s[2][HH];
    __shared__ float o4[2][48];
    __shared__ float fc0s[24 * 48];
    __shared__ float b1s[G4], b2s[G4];
    __shared__ float fc0bs[48], fc1bs[HH], fc2bs[48];
    __shared__ float st6[2][6], ac6[2][6];

    const int ctx = ctxp[0];

    // ---- init ----
    for (int i = tid; i < 24 * 48; i += 512) fc0s[i] = __uint_as_float(ws[OFF_FC0 + i]);
    for (int i = tid; i < G4; i += 512) {
        b1s[i] = __uint_as_float(ws[OFF_B1 + i]);
        b2s[i] = __uint_as_float(ws[OFF_B2 + i]);
    }
    if (tid < 48) fc0bs[tid] = fc0_b[tid];
    if (tid < HH) fc1bs[tid] = fc1_b[tid];
    if (tid < 48) fc2bs[tid] = fc2_b[tid];
    for (int i = tid; i < 2 * HH; i += 512) {
        int r = i / HH, f = i % HH;
        c1s[r][f] = 0.f; c2s[r][f] = 0.f;
        buf1[r][48 + f] = 0.f;           // h1 = 0
        buf2[r][f] = 0.f;                // h1 = 0
        buf2[r][248 + f] = 0.f;          // h2 = 0
        buf3[r][f] = 0.f;                // h2 = 0
    }
    for (int i = tid; i < 2 * 48; i += 512) {
        int r = i / 48, j = i % 48;
        buf2[r][200 + j] = 0.f; o4[r][j] = 0.f;
    }
    if (tid < 12) {                      // state = actions[0][row]
        int r = tid / 6, k = tid % 6;
        st6[r][k] = actions[(size_t)(r0 + r) * 6 + k];
    }
    __syncthreads();

    for (int t = 0; t < NSTEP; ++t) {
        // ---- phase X: x_t = (t<ctx) ? tactiles[t] : out4_{t-1}; fetch act_t ----
        if (tid < 96) {
            int r = tid / 48, j = tid % 48, row = r0 + r;
            float xv = (t < ctx) ? tactiles[((size_t)t * BB + row) * 48 + j] : o4[r][j];
            buf1[r][j] = xv;
            buf3[r][200 + j] = xv;
        } else if (tid < 108) {
            int q = tid - 96, r = q / 6, k = q % 6;
            ac6[r][k] = actions[((size_t)(t + 1) * BB + (r0 + r)) * 6 + k];
        }
        __syncthreads();

        // ---- gates1: [2][800] = buf1 @ W1cat (K=248) ----
        {
            const unsigned* Wp = ws + OFF_WP1;
            int c0 = tid;
            int c1c = (tid < G4 - 512) ? tid + 512 : -1;
            float a0 = b1s[c0], a1 = a0;
            float d0 = 0.f, d1 = 0.f;
            if (c1c >= 0) { d0 = b1s[c1c]; d1 = d0; }
            #pragma unroll 4
            for (int k2 = 0; k2 < 124; ++k2) {
                float xa0 = buf1[0][2 * k2], xb0 = buf1[0][2 * k2 + 1];
                float xa1 = buf1[1][2 * k2], xb1 = buf1[1][2 * k2 + 1];
                unsigned u0 = Wp[k2 * G4 + c0];
                float wl = unlo(u0), wh = unhi(u0);
                a0 += xa0 * wl + xb0 * wh;
                a1 += xa1 * wl + xb1 * wh;
                if (c1c >= 0) {
                    unsigned u1 = Wp[k2 * G4 + c1c];
                    float vl = unlo(u1), vh = unhi(u1);
                    d0 += xa0 * vl + xb0 * vh;
                    d1 += xa1 * vl + xb1 * vh;
                }
            }
            gbuf[0][c0] = a0; gbuf[1][c0] = a1;
            if (c1c >= 0) { gbuf[0][c1c] = d0; gbuf[1][c1c] = d1; }
        }
        __syncthreads();

        // ---- h1/c1 update (400 items) + out0 = relu(tiled@fc0^T) (96 items) ----
        if (tid < 400) {
            int r = tid / HH, f = tid % HH;
            float si = sigm(gbuf[r][f]);
            float sf = sigm(gbuf[r][200 + f]);
            float tg = tanhf(gbuf[r][400 + f]);
            float so = sigm(gbuf[r][600 + f]);
            float c = sf * c1s[r][f] + si * tg;
            c1s[r][f] = c;
            float h = so * tanhf(c);
            buf1[r][48 + f] = h;
            buf2[r][f] = h;
        } else if (tid < 496) {
            int q = tid - 400, r = q / 48, j = q % 48;
            float acc = fc0bs[j];
            #pragma unroll
            for (int k = 0; k < 24; ++k) {
                float tv = (k < 12) ? st6[r][k % 6] : ac6[r][k % 6];
                acc += tv * fc0s[k * 48 + j];
            }
            buf2[r][200 + j] = fmaxf(acc, 0.f);
        }
        __syncthreads();

        // ---- gates2: [2][800] = buf2 @ W2cat (K=448) ----
        {
            const unsigned* Wp = ws + OFF_WP2;
            int c0 = tid;
            int c1c = (tid < G4 - 512) ? tid + 512 : -1;
            float a0 = b2s[c0], a1 = a0;
            float d0 = 0.f, d1 = 0.f;
            if (c1c >= 0) { d0 = b2s[c1c]; d1 = d0; }
            #pragma unroll 4
            for (int k2 = 0; k2 < 224; ++k2) {
                float xa0 = buf2[0][2 * k2], xb0 = buf2[0][2 * k2 + 1];
                float xa1 = buf2[1][2 * k2], xb1 = buf2[1][2 * k2 + 1];
                unsigned u0 = Wp[k2 * G4 + c0];
                float wl = unlo(u0), wh = unhi(u0);
                a0 += xa0 * wl + xb0 * wh;
                a1 += xa1 * wl + xb1 * wh;
                if (c1c >= 0) {
                    unsigned u1 = Wp[k2 * G4 + c1c];
                    float vl = unlo(u1), vh = unhi(u1);
                    d0 += xa0 * vl + xb0 * vh;
                    d1 += xa1 * vl + xb1 * vh;
                }
            }
            gbuf[0][c0] = a0; gbuf[1][c0] = a1;
            if (c1c >= 0) { gbuf[0][c1c] = d0; gbuf[1][c1c] = d1; }
        }
        __syncthreads();

        // ---- h2/c2 update ----
        if (tid < 400) {
            int r = tid / HH, f = tid % HH;
            float si = sigm(gbuf[r][f]);
            float sf = sigm(gbuf[r][200 + f]);
            float tg = tanhf(gbuf[r][400 + f]);
            float so = sigm(gbuf[r][600 + f]);
            float c = sf * c2s[r][f] + si * tg;
            c2s[r][f] = c;
            float h = so * tanhf(c);
            buf2[r][248 + f] = h;
            buf3[r][f] = h;
        }
        __syncthreads();

        // ---- out3 = tanh([h2|x] @ fc1^T + b) (2 rows x 200) ----
        if (tid < 400) {
            int r = tid / HH, j = tid % HH;
            const unsigned* Wf = ws + OFF_WF1;
            float acc = fc1bs[j];
            #pragma unroll 4
            for (int k2 = 0; k2 < 124; ++k2) {
                unsigned u = Wf[k2 * HH + j];
                acc += buf3[r][2 * k2] * unlo(u) + buf3[r][2 * k2 + 1] * unhi(u);
            }
            o3[r][j] = tanhf(acc);
        }
        __syncthreads();

        // ---- out4 = tanh(out3 @ fc2^T + b) (2 rows x 48) + store ----
        if (tid < 96) {
            int r = tid / 48, j = tid % 48, row = r0 + r;
            const unsigned* Wf = ws + OFF_WF2;
            float acc = fc2bs[j];
            #pragma unroll 4
            for (int k2 = 0; k2 < 100; ++k2) {
                unsigned u = Wf[k2 * 48 + j];
                acc += o3[r][2 * k2] * unlo(u) + o3[r][2 * k2 + 1] * unhi(u);
            }
            float v = tanhf(acc);
            o4[r][j] = v;
            if (t >= ctx - 1) {
                out[((size_t)(t - (ctx - 1)) * BB + row) * 48 + j] = v;
            }
        }
        __syncthreads();
    }
}

extern "C" void kernel_launch(void* const* d_in, const int* in_sizes, int n_in,
                              void* d_out, int out_size, void* d_ws, size_t ws_size,
                              hipStream_t stream)
{
    const float* tactiles = (const float*)d_in[0];
    const float* actions  = (const float*)d_in[1];
    const float* fc0_w    = (const float*)d_in[2];
    const float* fc0_b    = (const float*)d_in[3];
    const float* l1_wih   = (const float*)d_in[4];
    const float* l1_whh   = (const float*)d_in[5];
    const float* l1_bih   = (const float*)d_in[6];
    const float* l1_bhh   = (const float*)d_in[7];
    const float* l2_wih   = (const float*)d_in[8];
    const float* l2_whh   = (const float*)d_in[9];
    const float* l2_bih   = (const float*)d_in[10];
    const float* l2_bhh   = (const float*)d_in[11];
    const float* fc1_w    = (const float*)d_in[12];
    const float* fc1_b    = (const float*)d_in[13];
    const float* fc2_w    = (const float*)d_in[14];
    const float* fc2_b    = (const float*)d_in[15];
    const int*   ctxp     = (const int*)d_in[16];
    unsigned* ws = (unsigned*)d_ws;
    float* out = (float*)d_out;

    hipLaunchKernelGGL(prep_kernel, dim3(512), dim3(256), 0, stream,
                       l1_wih, l1_whh, l1_bih, l1_bhh,
                       l2_wih, l2_whh, l2_bih, l2_bhh,
                       fc1_w, fc2_w, fc0_w, ws);
    hipLaunchKernelGGL(lstm_kernel, dim3(256), dim3(512), 0, stream,
                       tactiles, actions, fc0_b, fc1_b, fc2_b, ctxp, ws, out);
}

// Round 2
// 19965.364 us; speedup vs baseline: 1.9362x; 1.9362x over previous
//
#include <hip/hip_runtime.h>

typedef __attribute__((ext_vector_type(8))) short short8;
typedef __attribute__((ext_vector_type(4))) float floatx4;

#define TT    512
#define BB    512
#define HH    200
#define NSTEP 511
#define GW    808          // gates LDS row stride (f32), 808%32=8 -> spread banks

// ws layout (u32 words). Weights stored bf16, K-contiguous per output row, K padded to x32.
#define OFF_W1  0                      // [800][256] bf16: k 0..47 x, 48..247 h1, pad
#define LEN_W1  (800*128)
#define OFF_W2  (OFF_W1+LEN_W1)        // [800][448] bf16: k 0..199 h1, 200..247 out0, 248..447 h2
#define LEN_W2  (800*224)
#define OFF_F1  (OFF_W2+LEN_W2)        // [208][256] bf16: k 0..199 h2, 200..247 x, pad; rows 200..207 zero
#define LEN_F1  (208*128)
#define OFF_F2  (OFF_F1+LEN_F1)        // [48][224] bf16: k 0..199 o3, pad
#define LEN_F2  (48*112)
#define OFF_FC0 (OFF_F2+LEN_F2)        // [24][48] f32 fc0^T
#define OFF_B1  (OFF_FC0+1152)         // [800] f32 b1ih+b1hh
#define OFF_B2  (OFF_B1+800)           // [800] f32
#define WS_TOT  (OFF_B2+800)           // 316352 words = 1.27 MB

__device__ __forceinline__ unsigned short f2bf(float f) {
    unsigned u = __float_as_uint(f);
    unsigned r = (u + 0x7fffu + ((u >> 16) & 1u)) >> 16;
    return (unsigned short)r;
}
__device__ __forceinline__ float sigm(float x) { return 1.0f / (1.0f + __expf(-x)); }

// -------------------- prep: pack/transpose weights --------------------
__global__ void prep_kernel(const float* __restrict__ l1_wih, const float* __restrict__ l1_whh,
                            const float* __restrict__ l1_bih, const float* __restrict__ l1_bhh,
                            const float* __restrict__ l2_wih, const float* __restrict__ l2_whh,
                            const float* __restrict__ l2_bih, const float* __restrict__ l2_bhh,
                            const float* __restrict__ fc1_w, const float* __restrict__ fc2_w,
                            const float* __restrict__ fc0_w, unsigned* __restrict__ ws)
{
    int idx = blockIdx.x * blockDim.x + threadIdx.x;
    int stride = gridDim.x * blockDim.x;
    for (int i = idx; i < WS_TOT; i += stride) {
        if (i < OFF_W2) {
            int r = i - OFF_W1, n = r / 128, kp = r % 128;
            float a = 0.f, b = 0.f;
            int k0 = 2 * kp, k1 = k0 + 1;
            a = (k0 < 48) ? l1_wih[n*48 + k0] : (k0 < 248 ? l1_whh[n*HH + k0 - 48] : 0.f);
            b = (k1 < 48) ? l1_wih[n*48 + k1] : (k1 < 248 ? l1_whh[n*HH + k1 - 48] : 0.f);
            ws[i] = (unsigned)f2bf(a) | ((unsigned)f2bf(b) << 16);
        } else if (i < OFF_F1) {
            int r = i - OFF_W2, n = r / 224, kp = r % 224;
            int k0 = 2 * kp, k1 = k0 + 1;
            float a = (k0 < 248) ? l2_wih[n*248 + k0] : l2_whh[n*HH + k0 - 248];
            float b = (k1 < 248) ? l2_wih[n*248 + k1] : l2_whh[n*HH + k1 - 248];
            ws[i] = (unsigned)f2bf(a) | ((unsigned)f2bf(b) << 16);
        } else if (i < OFF_F2) {
            int r = i - OFF_F1, n = r / 128, kp = r % 128;
            int k0 = 2 * kp, k1 = k0 + 1;
            float a = (n < 200 && k0 < 248) ? fc1_w[n*248 + k0] : 0.f;
            float b = (n < 200 && k1 < 248) ? fc1_w[n*248 + k1] : 0.f;
            ws[i] = (unsigned)f2bf(a) | ((unsigned)f2bf(b) << 16);
        } else if (i < OFF_FC0) {
            int r = i - OFF_F2, n = r / 112, kp = r % 112;
            int k0 = 2 * kp, k1 = k0 + 1;
            float a = (k0 < 200) ? fc2_w[n*HH + k0] : 0.f;
            float b = (k1 < 200) ? fc2_w[n*HH + k1] : 0.f;
            ws[i] = (unsigned)f2bf(a) | ((unsigned)f2bf(b) << 16);
        } else if (i < OFF_B1) {
            int r = i - OFF_FC0, k = r / 48, j = r % 48;
            ws[i] = __float_as_uint(fc0_w[j*24 + k]);
        } else if (i < OFF_B2) {
            int j = i - OFF_B1;
            ws[i] = __float_as_uint(l1_bih[j] + l1_bhh[j]);
        } else {
            int j = i - OFF_B2;
            ws[i] = __float_as_uint(l2_bih[j] + l2_bhh[j]);
        }
    }
}

// write one bf16 element (row m, k-index k) into a pre-fragmented A-buffer
__device__ __forceinline__ void put16(short8* buf, int k, int m, unsigned short v) {
    int kt = k >> 5, kk = k & 31;
    ((unsigned short*)buf)[(((kt << 6) + m + ((kk >> 3) << 4)) << 3) + (kk & 7)] = v;
}

// MFMA phase: D[16][NT*16] = A(XA frags) * W^T rows, D -> gates (f32)
template<int KT, int KP8, int NT>
__device__ __forceinline__ void mm_phase(const short8* __restrict__ W, const short8* __restrict__ XA,
                                         float* __restrict__ g, int wave, int lane) {
    const int ln = lane & 15, hi = lane >> 4;
    for (int nt = wave; nt < NT; nt += 16) {
        const short8* wr = W + (size_t)(nt * 16 + ln) * KP8 + hi;
        floatx4 acc = {0.f, 0.f, 0.f, 0.f};
        #pragma unroll
        for (int kt = 0; kt < KT; ++kt) {
            short8 b = wr[kt * 4];
            short8 a = XA[(kt << 6) + lane];
            acc = __builtin_amdgcn_mfma_f32_16x16x32_bf16(a, b, acc, 0, 0, 0);
        }
        int col = nt * 16 + ln, m0 = hi * 4;
        g[(m0 + 0) * GW + col] = acc[0];
        g[(m0 + 1) * GW + col] = acc[1];
        g[(m0 + 2) * GW + col] = acc[2];
        g[(m0 + 3) * GW + col] = acc[3];
    }
}

// -------------------- main persistent kernel: 32 blocks x 1024 thr, 16 rows/block --------------------
__global__ __launch_bounds__(1024, 4)
void lstm_mfma(const float* __restrict__ tactiles, const float* __restrict__ actions,
               const float* __restrict__ fc0_b, const float* __restrict__ fc1_b,
               const float* __restrict__ fc2_b, const int* __restrict__ ctxp,
               const unsigned* __restrict__ wsu, float* __restrict__ out)
{
    const int tid = threadIdx.x;
    const int lane = tid & 63, wave = tid >> 6;
    const int r0 = blockIdx.x * 16;
    const int ctx = ctxp[0];

    const short8* W1 = (const short8*)(wsu + OFF_W1);
    const short8* W2 = (const short8*)(wsu + OFF_W2);
    const short8* F1 = (const short8*)(wsu + OFF_F1);
    const short8* F2 = (const short8*)(wsu + OFF_F2);

    __shared__ short8 XA1[8 * 64];    // gates1 in: x(0..47) h1(48..247) pad(248..255)
    __shared__ short8 XA2[14 * 64];   // gates2 in: h1(0..199) out0(200..247) h2(248..447)
    __shared__ short8 XA3[8 * 64];    // fc1 in:    h2(0..199) x(200..247) pad
    __shared__ short8 XA4[7 * 64];    // fc2 in:    o3(0..199) pad(200..223)
    __shared__ float gates[16 * GW];
    __shared__ float b1s[800], b2s[800], f1bs[200], f2bs[48], f0bs[48];
    __shared__ float fc0s[24 * 48];
    __shared__ float st6[16][6], ac6[16][6];

    // ---- init ----
    {
        short8 z = {0, 0, 0, 0, 0, 0, 0, 0};
        for (int i = tid; i < 37 * 64; i += 1024) {
            if (i < 8 * 64) XA1[i] = z;
            else if (i < 22 * 64) XA2[i - 8 * 64] = z;
            else if (i < 30 * 64) XA3[i - 22 * 64] = z;
            else XA4[i - 30 * 64] = z;
        }
    }
    for (int i = tid; i < 800; i += 1024) {
        b1s[i] = __uint_as_float(wsu[OFF_B1 + i]);
        b2s[i] = __uint_as_float(wsu[OFF_B2 + i]);
    }
    for (int i = tid; i < 1152; i += 1024) fc0s[i] = __uint_as_float(wsu[OFF_FC0 + i]);
    if (tid < 200) f1bs[tid] = fc1_b[tid];
    if (tid < 48) { f2bs[tid] = fc2_b[tid]; f0bs[tid] = fc0_b[tid]; }
    if (tid < 96) { int r = tid / 6, k = tid % 6; st6[r][k] = actions[(size_t)(r0 + r) * 6 + k]; }
    float c1r[4] = {0.f, 0.f, 0.f, 0.f};
    float c2r[4] = {0.f, 0.f, 0.f, 0.f};
    __syncthreads();

    for (int t = 0; t < NSTEP; ++t) {
        // ---- P0: x from tactiles (context phase only) ----
        if (t < ctx) {
            if (tid < 768) {
                int r = tid / 48, j = tid % 48;
                unsigned short xb = f2bf(tactiles[((size_t)t * BB + r0 + r) * 48 + j]);
                put16(XA1, j, r, xb);
                put16(XA3, 200 + j, r, xb);
            }
            __syncthreads();
        }

        // ---- P1: gates1 = X1 @ W1^T  (+ ac6 prefetch) ----
        mm_phase<8, 32, 50>(W1, XA1, gates, wave, lane);
        if (tid >= 928) {
            int q = tid - 928, r = q / 6, k = q % 6;
            ac6[r][k] = actions[((size_t)(t + 1) * BB + r0 + r) * 6 + k];
        }
        __syncthreads();

        // ---- P2: h1/c1 pointwise + out0 ----
        #pragma unroll
        for (int i = 0; i < 4; ++i) {
            int it = tid + 1024 * i;
            if (it < 3200) {
                int r = it / 200, f = it % 200;
                float gi = gates[r * GW + f]       + b1s[f];
                float gf = gates[r * GW + 200 + f] + b1s[200 + f];
                float gg = gates[r * GW + 400 + f] + b1s[400 + f];
                float go = gates[r * GW + 600 + f] + b1s[600 + f];
                float c = sigm(gf) * c1r[i] + sigm(gi) * tanhf(gg);
                c1r[i] = c;
                float h = sigm(go) * tanhf(c);
                unsigned short hb = f2bf(h);
                put16(XA1, 48 + f, r, hb);
                put16(XA2, f, r, hb);
            }
        }
        if (tid < 768) {
            int r = tid / 48, j = tid % 48;
            float acc = f0bs[j];
            #pragma unroll
            for (int k = 0; k < 24; ++k) {
                float tv = (k < 12) ? st6[r][k % 6] : ac6[r][k % 6];
                acc += tv * fc0s[k * 48 + j];
            }
            put16(XA2, 200 + j, r, f2bf(fmaxf(acc, 0.f)));
        }
        __syncthreads();

        // ---- P3: gates2 = X2 @ W2^T ----
        mm_phase<14, 56, 50>(W2, XA2, gates, wave, lane);
        __syncthreads();

        // ---- P4: h2/c2 pointwise ----
        #pragma unroll
        for (int i = 0; i < 4; ++i) {
            int it = tid + 1024 * i;
            if (it < 3200) {
                int r = it / 200, f = it % 200;
                float gi = gates[r * GW + f]       + b2s[f];
                float gf = gates[r * GW + 200 + f] + b2s[200 + f];
                float gg = gates[r * GW + 400 + f] + b2s[400 + f];
                float go = gates[r * GW + 600 + f] + b2s[600 + f];
                float c = sigm(gf) * c2r[i] + sigm(gi) * tanhf(gg);
                c2r[i] = c;
                float h = sigm(go) * tanhf(c);
                unsigned short hb = f2bf(h);
                put16(XA2, 248 + f, r, hb);
                put16(XA3, f, r, hb);
            }
        }
        __syncthreads();

        // ---- P5: fc1 out = X3 @ F1^T (13 tiles) ----
        mm_phase<8, 32, 13>(F1, XA3, gates, wave, lane);
        __syncthreads();

        // ---- P6: o3 = tanh(...) ----
        #pragma unroll
        for (int i = 0; i < 4; ++i) {
            int it = tid + 1024 * i;
            if (it < 3200) {
                int r = it / 200, f = it % 200;
                float v = tanhf(gates[r * GW + f] + f1bs[f]);
                put16(XA4, f, r, f2bf(v));
            }
        }
        __syncthreads();

        // ---- P7: fc2 out = X4 @ F2^T (3 tiles) ----
        mm_phase<7, 28, 3>(F2, XA4, gates, wave, lane);
        __syncthreads();

        // ---- P8: out4 = tanh(...), store, feed back as next x ----
        if (tid < 768) {
            int r = tid / 48, j = tid % 48;
            float v = tanhf(gates[r * GW + j] + f2bs[j]);
            if (t >= ctx - 1)
                out[((size_t)(t - (ctx - 1)) * BB + r0 + r) * 48 + j] = v;
            if (t + 1 >= ctx) {
                unsigned short xb = f2bf(v);
                put16(XA1, j, r, xb);
                put16(XA3, 200 + j, r, xb);
            }
        }
        __syncthreads();
    }
}

extern "C" void kernel_launch(void* const* d_in, const int* in_sizes, int n_in,
                              void* d_out, int out_size, void* d_ws, size_t ws_size,
                              hipStream_t stream)
{
    const float* tactiles = (const float*)d_in[0];
    const float* actions  = (const float*)d_in[1];
    const float* fc0_w    = (const float*)d_in[2];
    const float* fc0_b    = (const float*)d_in[3];
    const float* l1_wih   = (const float*)d_in[4];
    const float* l1_whh   = (const float*)d_in[5];
    const float* l1_bih   = (const float*)d_in[6];
    const float* l1_bhh   = (const float*)d_in[7];
    const float* l2_wih   = (const float*)d_in[8];
    const float* l2_whh   = (const float*)d_in[9];
    const float* l2_bih   = (const float*)d_in[10];
    const float* l2_bhh   = (const float*)d_in[11];
    const float* fc1_w    = (const float*)d_in[12];
    const float* fc1_b    = (const float*)d_in[13];
    const float* fc2_w    = (const float*)d_in[14];
    const float* fc2_b    = (const float*)d_in[15];
    const int*   ctxp     = (const int*)d_in[16];
    unsigned* ws = (unsigned*)d_ws;
    float* out = (float*)d_out;

    hipLaunchKernelGGL(prep_kernel, dim3(512), dim3(256), 0, stream,
                       l1_wih, l1_whh, l1_bih, l1_bhh,
                       l2_wih, l2_whh, l2_bih, l2_bhh,
                       fc1_w, fc2_w, fc0_w, ws);
    hipLaunchKernelGGL(lstm_mfma, dim3(32), dim3(1024), 0, stream,
                       tactiles, actions, fc0_b, fc1_b, fc2_b, ctxp, ws, out);
}